// Round 2
// baseline (86.541 us; speedup 1.0000x reference)
//
#include <hip/hip_runtime.h>

#define Bc 8
#define Nc 360
#define Dc 128
#define LDST 132   // LDS row stride (floats): 16B-aligned, bank-sweep-optimal for lane-owns-row reads

// Kernel 1: S[row,c] = emb[row,:] . W1[c, 0:128]
//           R[row,c] = emb[row,:] . W1[c, 128:256] + b1[c]
// Block: 64 rows (lane-mapped, LDS-staged) x 64 cols (16 per wave, wave-uniform -> scalar W1 loads)
__global__ __launch_bounds__(256) void proj_kernel(
    const float* __restrict__ emb, const float* __restrict__ W1,
    const float* __restrict__ b1, float* __restrict__ S, float* __restrict__ R)
{
    __shared__ float E_s[64 * LDST];
    const int t  = threadIdx.x;
    const int r0 = blockIdx.x * 64;

    // stage 64 emb rows, coalesced float4
    {
        const int rsub = t >> 5, c4 = (t & 31) * 4;
        #pragma unroll
        for (int p = 0; p < 8; ++p) {
            const int r = p * 8 + rsub;
            *reinterpret_cast<float4*>(&E_s[r * LDST + c4]) =
                *reinterpret_cast<const float4*>(&emb[(r0 + r) * Dc + c4]);
        }
    }
    __syncthreads();

    const int lane = t & 63;
    const int w    = __builtin_amdgcn_readfirstlane(t >> 6);   // wave id 0..3, forced SGPR
    const int c0   = blockIdx.y * 64 + w * 16;                 // uniform, 0..255 step 16
    const bool Shalf = (c0 < Dc);
    const int  cl    = Shalf ? c0 : (c0 - Dc);                 // local col 0..127, uniform
    const float* wbase = W1 + cl * (2 * Dc) + (Shalf ? 0 : Dc);

    float accv[16];
    #pragma unroll
    for (int cc = 0; cc < 16; ++cc)
        accv[cc] = Shalf ? 0.0f : b1[cl + cc];                 // uniform scalar load

    #pragma unroll 4
    for (int k4 = 0; k4 < 32; ++k4) {
        const float4 e = *reinterpret_cast<const float4*>(&E_s[lane * LDST + k4 * 4]);
        #pragma unroll
        for (int cc = 0; cc < 16; ++cc) {
            const float4 wv = *reinterpret_cast<const float4*>(wbase + cc * (2 * Dc) + k4 * 4);
            accv[cc] = fmaf(wv.x, e.x, accv[cc]);
            accv[cc] = fmaf(wv.y, e.y, accv[cc]);
            accv[cc] = fmaf(wv.z, e.z, accv[cc]);
            accv[cc] = fmaf(wv.w, e.w, accv[cc]);
        }
    }

    // each lane writes one full 64B line (16 contiguous floats)
    float* dst = (Shalf ? S : R) + (r0 + lane) * Dc + cl;
    #pragma unroll
    for (int q = 0; q < 4; ++q) {
        float4 o = make_float4(accv[q*4+0], accv[q*4+1], accv[q*4+2], accv[q*4+3]);
        reinterpret_cast<float4*>(dst)[q] = o;
    }
}

// Kernel 2: out[b,i,j] = relu( b2 + sum_d w2[d] * relu(R[b,i,d] + S[b,j,d]) )
// Block: 64 j (lane-mapped, LDS-staged S rows) x 36 i (9 per wave, uniform -> scalar R/w2 loads)
// Stores coalesced across lanes (j contiguous).
__global__ __launch_bounds__(256) void edge_kernel(
    const float* __restrict__ S, const float* __restrict__ R,
    const float* __restrict__ W2, const float* __restrict__ b2,
    float* __restrict__ out)
{
    __shared__ float S_s[64 * LDST];
    const int t  = threadIdx.x;
    const int b  = blockIdx.z;
    const int j0 = blockIdx.x * 64;
    const int i0 = blockIdx.y * 36;

    // stage S rows j0..j0+63 (clamped tail), coalesced float4
    {
        const int rsub = t >> 5, c4 = (t & 31) * 4;
        #pragma unroll
        for (int p = 0; p < 8; ++p) {
            const int r = p * 8 + rsub;
            int jr = j0 + r; if (jr > Nc - 1) jr = Nc - 1;
            *reinterpret_cast<float4*>(&S_s[r * LDST + c4]) =
                *reinterpret_cast<const float4*>(&S[(b * Nc + jr) * Dc + c4]);
        }
    }
    __syncthreads();

    const int lane = t & 63;
    const int w    = __builtin_amdgcn_readfirstlane(t >> 6);   // wave id 0..3
    const int iw   = i0 + w * 9;                               // uniform; 360 = 10*36 exact, no i tail
    const int jg   = j0 + lane;
    const bool jok = (jg < Nc);
    const float bias2 = b2[0];

    for (int g = 0; g < 3; ++g) {
        const int ia = iw + g * 3;
        const float* R0 = R + (b * Nc + ia + 0) * Dc;          // uniform pointers
        const float* R1 = R + (b * Nc + ia + 1) * Dc;
        const float* R2 = R + (b * Nc + ia + 2) * Dc;
        float a0 = 0.0f, a1 = 0.0f, a2 = 0.0f;

        #pragma unroll
        for (int k4 = 0; k4 < 32; ++k4) {
            const float4 sv  = *reinterpret_cast<const float4*>(&S_s[lane * LDST + k4 * 4]);
            const float4 wv  = *reinterpret_cast<const float4*>(W2 + k4 * 4);
            const float4 r0v = *reinterpret_cast<const float4*>(R0 + k4 * 4);
            const float4 r1v = *reinterpret_cast<const float4*>(R1 + k4 * 4);
            const float4 r2v = *reinterpret_cast<const float4*>(R2 + k4 * 4);
            a0 = fmaf(wv.x, fmaxf(r0v.x + sv.x, 0.0f), a0);
            a0 = fmaf(wv.y, fmaxf(r0v.y + sv.y, 0.0f), a0);
            a0 = fmaf(wv.z, fmaxf(r0v.z + sv.z, 0.0f), a0);
            a0 = fmaf(wv.w, fmaxf(r0v.w + sv.w, 0.0f), a0);
            a1 = fmaf(wv.x, fmaxf(r1v.x + sv.x, 0.0f), a1);
            a1 = fmaf(wv.y, fmaxf(r1v.y + sv.y, 0.0f), a1);
            a1 = fmaf(wv.z, fmaxf(r1v.z + sv.z, 0.0f), a1);
            a1 = fmaf(wv.w, fmaxf(r1v.w + sv.w, 0.0f), a1);
            a2 = fmaf(wv.x, fmaxf(r2v.x + sv.x, 0.0f), a2);
            a2 = fmaf(wv.y, fmaxf(r2v.y + sv.y, 0.0f), a2);
            a2 = fmaf(wv.z, fmaxf(r2v.z + sv.z, 0.0f), a2);
            a2 = fmaf(wv.w, fmaxf(r2v.w + sv.w, 0.0f), a2);
        }
        if (jok) {
            out[(b * Nc + ia + 0) * Nc + jg] = fmaxf(a0 + bias2, 0.0f);
            out[(b * Nc + ia + 1) * Nc + jg] = fmaxf(a1 + bias2, 0.0f);
            out[(b * Nc + ia + 2) * Nc + jg] = fmaxf(a2 + bias2, 0.0f);
        }
    }
}

extern "C" void kernel_launch(void* const* d_in, const int* in_sizes, int n_in,
                              void* d_out, int out_size, void* d_ws, size_t ws_size,
                              hipStream_t stream) {
    const float* emb = (const float*)d_in[0];   // [B,N,D]
    const float* W1  = (const float*)d_in[1];   // [D, 2D]
    const float* b1  = (const float*)d_in[2];   // [D]
    const float* W2  = (const float*)d_in[3];   // [1, D]
    const float* b2  = (const float*)d_in[4];   // [1]
    float* out = (float*)d_out;                 // [B,N,N,1]

    float* S = (float*)d_ws;                    // [B*N, D] sender proj
    float* R = S + Bc * Nc * Dc;                // [B*N, D] receiver proj (+b1)

    proj_kernel<<<dim3(Bc * Nc / 64, 4), 256, 0, stream>>>(emb, W1, b1, S, R);
    edge_kernel<<<dim3(6, 10, Bc), 256, 0, stream>>>(S, R, W2, b2, out);
}

// Round 3
// 37.094 us; speedup vs baseline: 2.3330x; 2.3330x over previous
//
#include <hip/hip_runtime.h>

#define Bc 8
#define Nc 360
#define Dc 128
#define LDST 132   // conflict-free stride (floats) for lane-owns-row b128 reads (verified: 0 conflicts r1/r2)

// proj: Bv[row,c] = w2_c * ( emb[row,:] . W1[c, 0:128] )              (sender,  j side)
//       Av[row,c] = w2_c * ( emb[row,:] . W1[c, 128:256] + b1[c] )    (receiver, i side)
// Block: 64 rows x 32 cols. All inner-loop operands in LDS (no SMEM/global in loop).
__global__ __launch_bounds__(256) void proj_kernel(
    const float* __restrict__ emb, const float* __restrict__ W1,
    const float* __restrict__ b1, const float* __restrict__ W2,
    float* __restrict__ Av, float* __restrict__ Bv)
{
    __shared__ float E_s[64 * LDST];     // emb rows, strided reads (lane = row)
    __shared__ float W_s[32 * Dc];       // W1 rows, uniform broadcast reads (tight stride fine)

    const int t  = threadIdx.x;
    const int r0 = blockIdx.x * 64;
    const int c0 = blockIdx.y * 32;              // 0..224
    const bool recv = (c0 >= Dc);
    const int  cl0  = recv ? (c0 - Dc) : c0;     // W1 row base / local col base
    const int  off  = recv ? Dc : 0;

    const int rsub = t >> 5, c4 = (t & 31) * 4;
    #pragma unroll
    for (int p = 0; p < 8; ++p) {
        const int r = p * 8 + rsub;
        *(float4*)&E_s[r * LDST + c4] = *(const float4*)&emb[(r0 + r) * Dc + c4];
    }
    #pragma unroll
    for (int p = 0; p < 4; ++p) {
        const int r = p * 8 + rsub;
        *(float4*)&W_s[r * Dc + c4] = *(const float4*)&W1[(cl0 + r) * (2 * Dc) + off + c4];
    }
    __syncthreads();

    const int lane = t & 63;
    const int wu   = __builtin_amdgcn_readfirstlane(t >> 6);   // wave 0..3, 8 cols each

    float acc[8];
    #pragma unroll
    for (int cc = 0; cc < 8; ++cc) acc[cc] = 0.0f;

    #pragma unroll 4
    for (int k4 = 0; k4 < 32; ++k4) {
        const float4 e = *(const float4*)&E_s[lane * LDST + k4 * 4];
        #pragma unroll
        for (int cc = 0; cc < 8; ++cc) {
            const float4 wv = *(const float4*)&W_s[(wu * 8 + cc) * Dc + k4 * 4]; // uniform bcast
            acc[cc] = fmaf(wv.x, e.x, acc[cc]);
            acc[cc] = fmaf(wv.y, e.y, acc[cc]);
            acc[cc] = fmaf(wv.z, e.z, acc[cc]);
            acc[cc] = fmaf(wv.w, e.w, acc[cc]);
        }
    }

    // epilogue: + b1 (recv), * w2; uniform scalar loads OK here (loop is done)
    float* dst = (recv ? Av : Bv) + (r0 + lane) * Dc + cl0 + wu * 8;
    #pragma unroll
    for (int cc = 0; cc < 8; ++cc) {
        const int c = cl0 + wu * 8 + cc;
        float v = recv ? (acc[cc] + b1[c]) : acc[cc];
        acc[cc] = v * W2[c];
    }
    #pragma unroll
    for (int q = 0; q < 2; ++q)
        ((float4*)dst)[q] = make_float4(acc[q*4+0], acc[q*4+1], acc[q*4+2], acc[q*4+3]);
}

// edge: out[b,i,j] = relu( b2 + rho_i + sig_j + sum_d s_d * |A[b,i,d] + B[b,j,d]| )
// Block: 64 j (lane-mapped) x 36 i (9 per wave, uniform LDS broadcasts). Grid 6x10x8.
__global__ __launch_bounds__(256) void edge_kernel(
    const float* __restrict__ Av, const float* __restrict__ Bv,
    const float* __restrict__ W2, const float* __restrict__ b2,
    float* __restrict__ out)
{
    __shared__ float B_s[64 * LDST];   // sender rows (lane-strided reads)
    __shared__ float A_s[36 * LDST];   // receiver rows (uniform reads; strided for rho pass)
    __shared__ float s_s[Dc];          // 0.5*sgn(w2_d)
    __shared__ float sig_s[64];
    __shared__ float rho_s[36];

    const int t  = threadIdx.x;
    const int b  = blockIdx.z;
    const int j0 = blockIdx.x * 64;
    const int i0 = blockIdx.y * 36;    // 360 = 10*36, no i tail

    const int rsub = t >> 5, c4 = (t & 31) * 4;
    #pragma unroll
    for (int p = 0; p < 8; ++p) {
        const int r = p * 8 + rsub;
        int jr = j0 + r; if (jr > Nc - 1) jr = Nc - 1;
        *(float4*)&B_s[r * LDST + c4] = *(const float4*)&Bv[(b * Nc + jr) * Dc + c4];
    }
    #pragma unroll
    for (int p = 0; p < 4; ++p) {
        const int r = p * 8 + rsub;
        *(float4*)&A_s[r * LDST + c4] = *(const float4*)&Av[(b * Nc + i0 + r) * Dc + c4];
    }
    if (rsub < 4) {
        const int r = 32 + rsub;
        *(float4*)&A_s[r * LDST + c4] = *(const float4*)&Av[(b * Nc + i0 + r) * Dc + c4];
    }
    __syncthreads();

    const int lane = t & 63;
    const int w    = t >> 6;
    // prologue: per-row sums and sign vector (each wave a disjoint task)
    if (w == 0) {
        float4 s = make_float4(0.f, 0.f, 0.f, 0.f);
        #pragma unroll 8
        for (int k4 = 0; k4 < 32; ++k4) {
            const float4 v = *(const float4*)&B_s[lane * LDST + k4 * 4];
            s.x += v.x; s.y += v.y; s.z += v.z; s.w += v.w;
        }
        sig_s[lane] = 0.5f * ((s.x + s.y) + (s.z + s.w));
    } else if (w == 1) {
        if (lane < 36) {
            float4 s = make_float4(0.f, 0.f, 0.f, 0.f);
            #pragma unroll 8
            for (int k4 = 0; k4 < 32; ++k4) {
                const float4 v = *(const float4*)&A_s[lane * LDST + k4 * 4];
                s.x += v.x; s.y += v.y; s.z += v.z; s.w += v.w;
            }
            rho_s[lane] = 0.5f * ((s.x + s.y) + (s.z + s.w));
        }
    } else if (w == 2) {
        s_s[lane] = copysignf(0.5f, W2[lane]);
    } else {
        s_s[64 + lane] = copysignf(0.5f, W2[64 + lane]);
    }
    __syncthreads();

    const int wu = __builtin_amdgcn_readfirstlane(w);   // force SGPR for uniform indexing
    float acc[9];
    #pragma unroll
    for (int q = 0; q < 9; ++q) acc[q] = 0.0f;

    #pragma unroll 4
    for (int k4 = 0; k4 < 32; ++k4) {
        const float4 bv = *(const float4*)&B_s[lane * LDST + k4 * 4];   // strided, conflict-free
        const float4 sv = *(const float4*)&s_s[k4 * 4];                 // uniform bcast
        #pragma unroll
        for (int q = 0; q < 9; ++q) {
            const float4 av = *(const float4*)&A_s[(wu * 9 + q) * LDST + k4 * 4]; // uniform bcast
            const float t0 = av.x + bv.x;
            const float t1 = av.y + bv.y;
            const float t2 = av.z + bv.z;
            const float t3 = av.w + bv.w;
            acc[q] = fmaf(sv.x, fabsf(t0), acc[q]);
            acc[q] = fmaf(sv.y, fabsf(t1), acc[q]);
            acc[q] = fmaf(sv.z, fabsf(t2), acc[q]);
            acc[q] = fmaf(sv.w, fabsf(t3), acc[q]);
        }
    }

    const int jg = j0 + lane;
    if (jg < Nc) {
        const float base = b2[0] + sig_s[lane];
        #pragma unroll
        for (int q = 0; q < 9; ++q) {
            const int ig = i0 + wu * 9 + q;
            out[(b * Nc + ig) * Nc + jg] = fmaxf(base + rho_s[wu * 9 + q] + acc[q], 0.0f);
        }
    }
}

extern "C" void kernel_launch(void* const* d_in, const int* in_sizes, int n_in,
                              void* d_out, int out_size, void* d_ws, size_t ws_size,
                              hipStream_t stream) {
    const float* emb = (const float*)d_in[0];   // [B,N,D]
    const float* W1  = (const float*)d_in[1];   // [D, 2D]
    const float* b1  = (const float*)d_in[2];   // [D]
    const float* W2  = (const float*)d_in[3];   // [1, D]
    const float* b2  = (const float*)d_in[4];   // [1]
    float* out = (float*)d_out;                 // [B,N,N,1]

    float* Av = (float*)d_ws;                   // [B*N, D] w2-scaled receiver proj (+b1)
    float* Bv = Av + Bc * Nc * Dc;              // [B*N, D] w2-scaled sender proj

    proj_kernel<<<dim3(Bc * Nc / 64, 8), 256, 0, stream>>>(emb, W1, b1, W2, Av, Bv);
    edge_kernel<<<dim3(6, 10, Bc), 256, 0, stream>>>(Av, Bv, W2, b2, out);
}